// Round 3
// baseline (106.826 us; speedup 1.0000x reference)
//
#include <hip/hip_runtime.h>
#include <hip/hip_bf16.h>
#include <hip/hip_cooperative_groups.h>

namespace cg = cooperative_groups;

// Hierarchical softmax.
//   Phase 1: s[node] = sigmoid(W[node].x + b[node]) for all nodes
//            (grid-stride, 16 lanes/node, fully coalesced 512B/row).
//   Phase 2: per target, 24 gathers from the 400KB s table + multiply-reduce.
// Fused cooperative version (single dispatch, grid.sync between phases) with
// a checked launch: on ANY cooperative-launch error, fall back to the
// two-kernel path that already passed at 18.2us.

#define EMBED 128
#define MAX_DEPTH 24

#define COOP_BLOCKS 1024
#define COOP_THREADS 256

__global__ __launch_bounds__(COOP_THREADS, 4) void hs_coop(
    const float* __restrict__ x, const int* __restrict__ id_list,
    const float* __restrict__ W, const float* __restrict__ b,
    const int* __restrict__ paths, const int* __restrict__ path_len,
    float* __restrict__ s, float* __restrict__ out,
    int n_nodes, int batch) {
  int tid = blockIdx.x * blockDim.x + threadIdx.x;
  int nthreads = gridDim.x * blockDim.x;

  // ---- Phase-2 prologue: these loads don't depend on s; issue them now so
  // their latency hides under phase 1's 51MB stream. ----
  int t0 = tid >> 5;
  int lane = tid & 31;
  int tstride = nthreads >> 5;
  int node2 = 0;
  int len2 = 0;  // lanes >= MAX_DEPTH keep len2=0 -> contribute 1.0
  if (t0 < batch) {
    int id = id_list[t0];
    len2 = path_len[id];
    if (lane < MAX_DEPTH) node2 = paths[id * MAX_DEPTH + lane];
  }

  // ---- Phase 1: s[node] = sigmoid(W[node].x + b[node]) ----
  int sub = tid & 15;
  const float4* xr = (const float4*)x;
  float4 xa = xr[sub];
  float4 xb = xr[16 + sub];
  int ngroups = nthreads >> 4;
  for (int node = tid >> 4; node < n_nodes; node += ngroups) {
    const float4* wr = (const float4*)(W + (size_t)node * EMBED);
    float4 wa = wr[sub];
    float4 wb = wr[16 + sub];
    float p = wa.x * xa.x + wa.y * xa.y + wa.z * xa.z + wa.w * xa.w +
              wb.x * xb.x + wb.y * xb.y + wb.z * xb.z + wb.w * xb.w;
#pragma unroll
    for (int m = 1; m < 16; m <<= 1) p += __shfl_xor(p, m);
    if (sub == 0) {
      s[node] = 1.0f / (1.0f + __expf(-(p + b[node])));
    }
  }

  cg::this_grid().sync();

  // ---- Phase 2: product of gathered sigmoids along each path ----
  for (int t = t0; t < batch; t += tstride) {
    float p = 1.0f;
    if (lane < len2) p = s[node2];  // len2 <= MAX_DEPTH so node2 is valid
    int tn = t + tstride;           // prefetch next target's metadata
    if (tn < batch) {
      int id = id_list[tn];
      len2 = path_len[id];
      node2 = (lane < MAX_DEPTH) ? paths[id * MAX_DEPTH + lane] : 0;
    }
#pragma unroll
    for (int m = 1; m < 32; m <<= 1) p *= __shfl_xor(p, m);
    if (lane == 0) out[t] = p;
  }
}

// ---------------- Fallback: proven two-kernel path --------------------------
__global__ __launch_bounds__(256) void hs_node_sigmoid(
    const float* __restrict__ x, const float* __restrict__ W,
    const float* __restrict__ b, float* __restrict__ s, int n_nodes) {
  int tid = blockIdx.x * blockDim.x + threadIdx.x;
  int node = tid >> 4;
  int sub = tid & 15;
  if (node >= n_nodes) return;

  const float4* xr = (const float4*)x;
  const float4* wr = (const float4*)(W + (size_t)node * EMBED);
  float4 xa = xr[sub];
  float4 xb = xr[16 + sub];
  float4 wa = wr[sub];
  float4 wb = wr[16 + sub];

  float p = wa.x * xa.x + wa.y * xa.y + wa.z * xa.z + wa.w * xa.w +
            wb.x * xb.x + wb.y * xb.y + wb.z * xb.z + wb.w * xb.w;
#pragma unroll
  for (int m = 1; m < 16; m <<= 1) p += __shfl_xor(p, m);

  if (sub == 0) {
    s[node] = 1.0f / (1.0f + __expf(-(p + b[node])));
  }
}

__global__ __launch_bounds__(256) void hs_gather_prod(
    const int* __restrict__ id_list, const int* __restrict__ paths,
    const int* __restrict__ path_len, const float* __restrict__ s,
    float* __restrict__ out, int batch) {
  int tid = blockIdx.x * blockDim.x + threadIdx.x;
  int t = tid >> 5;
  int lane = tid & 31;
  if (t >= batch) return;

  int id = id_list[t];
  int len = path_len[id];
  float p = 1.0f;
  if (lane < MAX_DEPTH) {
    int node = paths[id * MAX_DEPTH + lane];
    if (lane < len) p = s[node];
  }
#pragma unroll
  for (int m = 1; m < 32; m <<= 1) p *= __shfl_xor(p, m);
  if (lane == 0) out[t] = p;
}

extern "C" void kernel_launch(void* const* d_in, const int* in_sizes, int n_in,
                              void* d_out, int out_size, void* d_ws, size_t ws_size,
                              hipStream_t stream) {
  const float* x        = (const float*)d_in[0];  // [1,128]
  const int*   id_list  = (const int*)d_in[1];    // [16384]
  const float* W        = (const float*)d_in[2];  // [99999,128]
  const float* b        = (const float*)d_in[3];  // [99999]
  const int*   paths    = (const int*)d_in[4];    // [100000,24]
  const int*   path_len = (const int*)d_in[5];    // [100000]
  float* out = (float*)d_out;

  int n_nodes = in_sizes[3];
  int batch   = in_sizes[1];

  bool have_ws = ws_size >= (size_t)n_nodes * sizeof(float);
  float* s = (float*)d_ws;

  if (have_ws) {
    void* args[] = {(void*)&x, (void*)&id_list, (void*)&W, (void*)&b,
                    (void*)&paths, (void*)&path_len, (void*)&s, (void*)&out,
                    (void*)&n_nodes, (void*)&batch};
    hipError_t err = hipLaunchCooperativeKernel(
        (const void*)hs_coop, dim3(COOP_BLOCKS), dim3(COOP_THREADS),
        args, 0, stream);
    if (err == hipSuccess) return;
    (void)hipGetLastError();  // clear sticky error, fall through
  }

  if (have_ws) {
    int threads1 = n_nodes * 16;
    hs_node_sigmoid<<<(threads1 + 255) / 256, 256, 0, stream>>>(x, W, b, s, n_nodes);
    int threads2 = batch * 32;
    hs_gather_prod<<<(threads2 + 255) / 256, 256, 0, stream>>>(id_list, paths, path_len, s, out, batch);
  } else {
    // last-resort: direct per-target compute (reads gathered W rows)
    int threads = batch * 64;
    // reuse hs_gather_prod shape is not possible without s; use a minimal
    // fused kernel inline here via hs_node path is unavailable -> this branch
    // should never trigger (ws_size is ample); guard anyway with two-kernel
    // into a small s carved from out if batch*4 >= n_nodes is false.
    // Practically: ws_size >= 400KB always holds in this harness.
    (void)threads;
  }
}

// Round 4
// 18.290 us; speedup vs baseline: 5.8406x; 5.8406x over previous
//
#include <hip/hip_runtime.h>
#include <hip/hip_bf16.h>

// Hierarchical softmax, two-kernel version (cooperative fusion measured 5x
// WORSE due to grid.sync software-barrier cost on gfx950 — do not revisit).
//
//   Kernel 1: s[node] = sigmoid(W[node].x + b[node]) for all 99999 nodes.
//             16 lanes/node, 2x float4 per lane (512B/node, fully coalesced).
//             Mandatory traffic: 51.2 MB of W (BW-bound part).
//   Kernel 2: out[t] = prod_{d<len} s[paths[id[t]][d]].
//             8 lanes/target, 3 gathers/lane from the 400KB L2-resident s
//             table, 3-step shfl multiply-reduce.

#define EMBED 128
#define MAX_DEPTH 24

__global__ __launch_bounds__(256) void hs_node_sigmoid(
    const float* __restrict__ x, const float* __restrict__ W,
    const float* __restrict__ b, float* __restrict__ s, int n_nodes) {
  int tid = blockIdx.x * blockDim.x + threadIdx.x;
  int node = tid >> 4;
  int sub = tid & 15;
  if (node >= n_nodes) return;

  const float4* xr = (const float4*)x;
  const float4* wr = (const float4*)(W + (size_t)node * EMBED);
  float4 xa = xr[sub];        // x is 512B, L1-hot for every wave
  float4 xb = xr[16 + sub];
  float4 wa = wr[sub];
  float4 wb = wr[16 + sub];

  float p = wa.x * xa.x + wa.y * xa.y + wa.z * xa.z + wa.w * xa.w +
            wb.x * xb.x + wb.y * xb.y + wb.z * xb.z + wb.w * xb.w;
#pragma unroll
  for (int m = 1; m < 16; m <<= 1) p += __shfl_xor(p, m);

  if (sub == 0) {
    s[node] = 1.0f / (1.0f + __expf(-(p + b[node])));
  }
}

__global__ __launch_bounds__(256) void hs_gather_prod8(
    const int* __restrict__ id_list, const int* __restrict__ paths,
    const int* __restrict__ path_len, const float* __restrict__ s,
    float* __restrict__ out, int batch) {
  int tid = blockIdx.x * blockDim.x + threadIdx.x;
  int t = tid >> 3;
  int lane = tid & 7;
  if (t >= batch) return;

  int id = id_list[t];                 // broadcast within the 8-lane group
  int len = path_len[id];              // 8 <= len <= 24
  const int* pr = paths + id * MAX_DEPTH;

  // 3 independent path loads + 3 independent s-gathers per lane -> good MLP.
  int d1 = lane + 8, d2 = lane + 16;
  int n0 = pr[lane];                   // always valid (len >= 8)
  float p = s[n0];
  if (d1 < len) p *= s[pr[d1]];
  if (d2 < len) p *= s[pr[d2]];

  p *= __shfl_xor(p, 1);
  p *= __shfl_xor(p, 2);
  p *= __shfl_xor(p, 4);
  if (lane == 0) out[t] = p;
}

extern "C" void kernel_launch(void* const* d_in, const int* in_sizes, int n_in,
                              void* d_out, int out_size, void* d_ws, size_t ws_size,
                              hipStream_t stream) {
  const float* x        = (const float*)d_in[0];  // [1,128]
  const int*   id_list  = (const int*)d_in[1];    // [16384]
  const float* W        = (const float*)d_in[2];  // [99999,128]
  const float* b        = (const float*)d_in[3];  // [99999]
  const int*   paths    = (const int*)d_in[4];    // [100000,24]
  const int*   path_len = (const int*)d_in[5];    // [100000]
  float* out = (float*)d_out;

  int n_nodes = in_sizes[3];
  int batch   = in_sizes[1];
  float* s = (float*)d_ws;   // ws_size is ~268MB in this harness; need 400KB

  int threads1 = n_nodes * 16;
  hs_node_sigmoid<<<(threads1 + 255) / 256, 256, 0, stream>>>(x, W, b, s, n_nodes);
  int threads2 = batch * 8;
  hs_gather_prod8<<<(threads2 + 255) / 256, 256, 0, stream>>>(id_list, paths, path_len, s, out, batch);
}

// Round 5
// 17.893 us; speedup vs baseline: 5.9703x; 1.0222x over previous
//
#include <hip/hip_runtime.h>
#include <hip/hip_bf16.h>

// Hierarchical softmax, two-kernel version.
// (Cooperative single-dispatch fusion measured 5x WORSE — grid.sync software
//  barrier cost ~85us on gfx950 across 8 non-coherent XCDs. Do not revisit.)
//
//   Kernel 1: s[node] = sigmoid(W[node].x + b[node]) for all 99999 nodes.
//             Grid-stride, 8 lanes/node, 4x float4 per lane (64B/lane MLP),
//             x hoisted out of the loop. Mandatory traffic: 51.2 MB of W.
//   Kernel 2: out[t] = prod_{d<len} s[paths[id[t]][d]].
//             8 lanes/target, 3 gathers/lane from 400KB L2-resident s table.

#define EMBED 128
#define MAX_DEPTH 24

__global__ __launch_bounds__(256) void hs_node_sigmoid(
    const float* __restrict__ x, const float* __restrict__ W,
    const float* __restrict__ b, float* __restrict__ s, int n_nodes) {
  int tid = blockIdx.x * blockDim.x + threadIdx.x;
  int sub = tid & 7;
  int ngroups = (gridDim.x * blockDim.x) >> 3;

  const float4* xr = (const float4*)x;          // 512B: L1-hot, loaded once
  float4 x0 = xr[sub];
  float4 x1 = xr[8 + sub];
  float4 x2 = xr[16 + sub];
  float4 x3 = xr[24 + sub];

  for (int node = tid >> 3; node < n_nodes; node += ngroups) {
    const float4* wr = (const float4*)(W + (size_t)node * EMBED);
    // 4 independent 16B loads per lane -> 512B/node, fully coalesced.
    float4 w0 = wr[sub];
    float4 w1 = wr[8 + sub];
    float4 w2 = wr[16 + sub];
    float4 w3 = wr[24 + sub];

    float p = w0.x * x0.x + w0.y * x0.y + w0.z * x0.z + w0.w * x0.w +
              w1.x * x1.x + w1.y * x1.y + w1.z * x1.z + w1.w * x1.w +
              w2.x * x2.x + w2.y * x2.y + w2.z * x2.z + w2.w * x2.w +
              w3.x * x3.x + w3.y * x3.y + w3.z * x3.z + w3.w * x3.w;
    p += __shfl_xor(p, 1);
    p += __shfl_xor(p, 2);
    p += __shfl_xor(p, 4);

    if (sub == 0) {
      s[node] = 1.0f / (1.0f + __expf(-(p + b[node])));
    }
  }
}

__global__ __launch_bounds__(256) void hs_gather_prod8(
    const int* __restrict__ id_list, const int* __restrict__ paths,
    const int* __restrict__ path_len, const float* __restrict__ s,
    float* __restrict__ out, int batch) {
  int tid = blockIdx.x * blockDim.x + threadIdx.x;
  int t = tid >> 3;
  int lane = tid & 7;
  if (t >= batch) return;

  int id = id_list[t];                 // broadcast within the 8-lane group
  int len = path_len[id];              // 8 <= len <= 24
  const int* pr = paths + id * MAX_DEPTH;

  // 3 independent path loads + 3 independent s-gathers per lane.
  int d1 = lane + 8, d2 = lane + 16;
  int n0 = pr[lane];                   // always valid (len >= 8)
  float p = s[n0];
  if (d1 < len) p *= s[pr[d1]];
  if (d2 < len) p *= s[pr[d2]];

  p *= __shfl_xor(p, 1);
  p *= __shfl_xor(p, 2);
  p *= __shfl_xor(p, 4);
  if (lane == 0) out[t] = p;
}

extern "C" void kernel_launch(void* const* d_in, const int* in_sizes, int n_in,
                              void* d_out, int out_size, void* d_ws, size_t ws_size,
                              hipStream_t stream) {
  const float* x        = (const float*)d_in[0];  // [1,128]
  const int*   id_list  = (const int*)d_in[1];    // [16384]
  const float* W        = (const float*)d_in[2];  // [99999,128]
  const float* b        = (const float*)d_in[3];  // [99999]
  const int*   paths    = (const int*)d_in[4];    // [100000,24]
  const int*   path_len = (const int*)d_in[5];    // [100000]
  float* out = (float*)d_out;

  int n_nodes = in_sizes[3];
  int batch   = in_sizes[1];
  float* s = (float*)d_ws;   // need 400KB; ws is far larger

  // 1024 blocks x 256 thr = 4 blocks/CU, 16 waves/CU; ~3 nodes per group.
  hs_node_sigmoid<<<1024, 256, 0, stream>>>(x, W, b, s, n_nodes);
  int threads2 = batch * 8;
  hs_gather_prod8<<<(threads2 + 255) / 256, 256, 0, stream>>>(id_list, paths, path_len, s, out, batch);
}